// Round 4
// baseline (94.296 us; speedup 1.0000x reference)
//
#include <hip/hip_runtime.h>

// CTC batch cost (Keras semantics, blank = C-1). B=1024, T=256, C=128, L=48, S=97.
// One wave per batch element; lane l owns alpha[2l] (blank, a0) and alpha[2l+1]
// (label, a1). Probability-domain DP with stale-by-RS adaptive rescaling:
//   a0' = (a0 + a1[l-1]) * (p_blank + eps)
//   a1' = (a1 + a0 + cs * a1[l-1]) * (p_label + eps)
// Each lane loads ONLY its own label's prob per row (lanes>=48 load blank).

#define TT 256
#define CC 128
#define LL 48
#define PF 16   // register prefetch depth (steps); divides TT
#define RS 4    // rescale interval (steps); divides PF

__global__ __launch_bounds__(256) void ctc_fwd_prob(
    const float* __restrict__ y,       // [B, T, C] softmax probs
    const int* __restrict__ labels,    // [B, L]
    float* __restrict__ out)           // [B]
{
    const int lane = threadIdx.x & 63;
    const int wave = threadIdx.x >> 6;
    const int b = blockIdx.x * 4 + wave;
    const float EPS = 1e-7f;

    // Per-lane class: label for odd position s=2*lane+1 (lanes 0..47), blank else.
    int lab = CC - 1;
    if (lane < LL) lab = labels[b * LL + lane];
    const int labprev = __shfl_up(lab, 1);
    const bool cs = (lane > 0) && (lane < LL) && (lab != labprev);

    const float* p = y + (size_t)b * TT * CC + lab;  // per-lane column pointer

    // Register prefetch ring: one float per step (this lane's class prob).
    float pr[PF];
#pragma unroll
    for (int i = 0; i < PF; ++i) pr[i] = p[(size_t)i * CC];

    float a0 = (lane == 0) ? 1.0f : 0.0f;  // so the uniform t=0 update yields alpha0
    float a1 = 0.0f;
    float lg = 0.0f;      // accumulated log2 of applied scales
    float mpend = 1.0f;   // stale max (computed at previous rescale point)

    for (int t = 0; t < TT; t += PF) {
#pragma unroll
        for (int j = 0; j < PF; ++j) {
            if ((j & (RS - 1)) == 0) {
                // Apply the stale max from RS steps ago, then start a new butterfly.
                const float r = 1.0f / mpend;
                lg += __log2f(mpend);
                a0 *= r;
                a1 *= r;
                float m = fmaxf(a0, a1);
                m = fmaxf(m, __shfl_xor(m, 1));
                m = fmaxf(m, __shfl_xor(m, 2));
                m = fmaxf(m, __shfl_xor(m, 4));
                m = fmaxf(m, __shfl_xor(m, 8));
                m = fmaxf(m, __shfl_xor(m, 16));
                m = fmaxf(m, __shfl_xor(m, 32));
                mpend = m;  // consumed RS steps later; chain overlaps DP work
            }

            const float pld = pr[j];            // this step's prob (loaded PF ago)
            const int tn = t + j + PF;
            if (tn < TT) pr[j] = p[(size_t)tn * CC];   // refill ring
            asm volatile("" ::: "memory");      // pin load issue order (no sinking)

            const float pb = __shfl(pld, 63) + EPS;    // blank prob (lane 63 owns it)
            const float pl = pld + EPS;
            float pp = __shfl_up(a1, 1);               // alpha[2l-1] (old)
            if (lane == 0) pp = 0.0f;

            const float a0old = a0;
            a0 = (a0old + pp) * pb;
            a1 = (a1 + a0old + (cs ? pp : 0.0f)) * pl;
        }
    }

    // loss = -( log(alpha[95] + alpha[96]) + lg*ln2 )
    const float v95 = __shfl(a1, 47);
    const float v96 = __shfl(a0, 48);
    if (lane == 0) {
        const float s = fmaxf(v95 + v96, 1e-37f);
        out[b] = -(__logf(s) + lg * 0.69314718056f);
    }
}

extern "C" void kernel_launch(void* const* d_in, const int* in_sizes, int n_in,
                              void* d_out, int out_size, void* d_ws, size_t ws_size,
                              hipStream_t stream) {
    const float* y = (const float*)d_in[0];
    const int* labels = (const int*)d_in[1];
    float* out = (float*)d_out;
    const int B = in_sizes[0] / (TT * CC);   // 1024
    ctc_fwd_prob<<<B / 4, 256, 0, stream>>>(y, labels, out);
}

// Round 5
// 91.792 us; speedup vs baseline: 1.0273x; 1.0273x over previous
//
#include <hip/hip_runtime.h>

// CTC batch cost (Keras, blank=C-1). B=1024, T=256, C=128, L=48, S=97.
// One wave per batch element; lane l owns alpha[2l] (a0, blank pos) and
// alpha[2l+1] (a1, label pos). Probability-domain DP:
//   a0' = (a0 + a1[l-1]) * pb ;  a1' = (a1 + a0 + cs*a1[l-1]) * pl
// Cross-lane a1[l-1] via DPP row_shr:1 + v_readlane fixups (NO ds ops in loop).
// Exact exponent rescale (frexp/ldexp) every RS steps via DPP max-reduce.

#define TT 256
#define CC 128
#define LL 48
#define PF 16   // register prefetch ring depth (steps)
#define RS 8    // rescale interval (divides PF)

template<int CTRL>
__device__ __forceinline__ float dpp_mv(float x) {
    union { float f; int i; } u, r;
    u.f = x;
    r.i = __builtin_amdgcn_update_dpp(0, u.i, CTRL, 0xF, 0xF, false); // OOB lanes -> 0
    return r.f;
}

__device__ __forceinline__ float rdlane(float x, int l) {
    union { float f; int i; } u, r;
    u.f = x;
    r.i = __builtin_amdgcn_readlane(u.i, l);
    return r.f;
}

__global__ __launch_bounds__(256) void ctc_fwd_dpp(
    const float* __restrict__ y,       // [B, T, C] softmax probs
    const int* __restrict__ labels,    // [B, L]
    float* __restrict__ out)           // [B]
{
    const int lane = threadIdx.x & 63;
    const int wave = threadIdx.x >> 6;
    const int b = blockIdx.x * 4 + wave;
    const float EPS = 1e-7f;

    int lab = CC - 1;
    if (lane < LL) lab = labels[b * LL + lane];
    const int labprev = __shfl_up(lab, 1);                 // once, outside loop
    const bool cs = (lane > 0) && (lane < LL) && (lab != labprev);
    const bool is16 = (lane == 16), is32 = (lane == 32), is48 = (lane == 48);

    const float* pl_ptr = y + (size_t)b * TT * CC + lab;       // per-lane label col
    const float* pb_ptr = y + (size_t)b * TT * CC + (CC - 1);  // blank col (uniform)

    float prl[PF], prb[PF];
#pragma unroll
    for (int i = 0; i < PF; ++i) {
        prl[i] = pl_ptr[(size_t)i * CC];
        prb[i] = pb_ptr[(size_t)i * CC];
    }

    float a0 = (lane == 0) ? 1.0f : 0.0f;   // uniform t=0 update then yields alpha0
    float a1 = 0.0f;
    int lg = 0;                              // accumulated log2 scale (exact ints)

    for (int t = 0; t < TT; t += PF) {
#pragma unroll
        for (int j = 0; j < PF; ++j) {
            const float pl = prl[j] + EPS;
            const float pb = prb[j] + EPS;
            const int tn = t + j + PF;
            if (tn < TT) {                   // refill ring (used PF steps later)
                prl[j] = pl_ptr[(size_t)tn * CC];
                prb[j] = pb_ptr[(size_t)tn * CC];
            }

            float pp = dpp_mv<0x111>(a1);    // a1[l-1]; rows' lane0 -> 0
            const float s15 = rdlane(a1, 15);
            const float s31 = rdlane(a1, 31);
            const float s47 = rdlane(a1, 47);
            if (is16) pp = s15;
            if (is32) pp = s31;
            if (is48) pp = s47;              // lane 0 keeps 0 (alpha[-1]=0)

            const float a0old = a0;
            a0 = (a0old + pp) * pb;
            a1 = (a1 + a0old + (cs ? pp : 0.0f)) * pl;

            if ((j & (RS - 1)) == (RS - 1)) {
                // wave-wide max via DPP (VALU-speed), then exact 2^-e rescale
                float m = fmaxf(a0, a1);
                m = fmaxf(m, dpp_mv<0x111>(m));   // row_shr:1
                m = fmaxf(m, dpp_mv<0x112>(m));   // row_shr:2
                m = fmaxf(m, dpp_mv<0x114>(m));   // row_shr:4
                m = fmaxf(m, dpp_mv<0x118>(m));   // row_shr:8  (lane15+16k = row max)
                m = fmaxf(m, dpp_mv<0x142>(m));   // row_bcast:15
                m = fmaxf(m, dpp_mv<0x143>(m));   // row_bcast:31 (lane63 = global)
                const float mm = rdlane(m, 63);
                int e;
                (void)frexpf(mm, &e);             // mm = f*2^e, f in [0.5,1)
                a0 = ldexpf(a0, -e);
                a1 = ldexpf(a1, -e);
                lg += e;
            }
        }
        asm volatile("" ::: "memory");  // pin ring loads to their outer iter only
    }

    // loss = -log(alpha[95] + alpha[96]) - lg*ln2
    const float v95 = rdlane(a1, 47);   // s = 95
    const float v96 = rdlane(a0, 48);   // s = 96
    if (lane == 0) {
        const float s = fmaxf(v95 + v96, 1e-37f);
        out[b] = -(__logf(s) + (float)lg * 0.69314718056f);
    }
}

extern "C" void kernel_launch(void* const* d_in, const int* in_sizes, int n_in,
                              void* d_out, int out_size, void* d_ws, size_t ws_size,
                              hipStream_t stream) {
    const float* y = (const float*)d_in[0];
    const int* labels = (const int*)d_in[1];
    float* out = (float*)d_out;
    const int B = in_sizes[0] / (TT * CC);   // 1024
    ctc_fwd_dpp<<<B / 4, 256, 0, stream>>>(y, labels, out);
}

// Round 6
// 29.352 us; speedup vs baseline: 3.2126x; 3.1273x over previous
//
#include <hip/hip_runtime.h>

// CTC batch cost (Keras, blank=C-1). B=1024, T=256, C=128, L=48, S=97.
// One wave per batch element; lane l owns alpha[2l] (a0) / alpha[2l+1] (a1).
// Probability-domain DP, exact 2^-e rescale every 8 steps (DPP max butterfly).
// Loads: ONE stream (lane's class prob; lanes>=48 carry blank), batch-clustered
// 16 at a time, triple-buffered (A/B/C), consumed 2 bodies (~1400cy) later.
// Value-only asm pins stop load sinking WITHOUT a vmcnt(0) drain.

#define TT 256
#define CC 128
#define LL 48
#define BS 16          // steps per body
#define NB (TT / BS)   // 16 bodies

template<int CTRL>
__device__ __forceinline__ float dpp_mv(float x) {
    union { float f; int i; } u, r;
    u.f = x;
    r.i = __builtin_amdgcn_update_dpp(0, u.i, CTRL, 0xF, 0xF, false); // shifted-in -> 0
    return r.f;
}
__device__ __forceinline__ float rdlane(float x, int l) {
    union { float f; int i; } u, r;
    u.f = x;
    r.i = __builtin_amdgcn_readlane(u.i, l);
    return r.f;
}

__global__ __launch_bounds__(256) void ctc_fwd_v6(
    const float* __restrict__ y,       // [B, T, C]
    const int* __restrict__ labels,    // [B, L]
    float* __restrict__ out)           // [B]
{
    const int lane = threadIdx.x & 63;
    const int wave = threadIdx.x >> 6;
    const int b = blockIdx.x * 4 + wave;
    const float EPS = 1e-7f;

    int lab = CC - 1;                                  // lanes >= LL carry blank
    if (lane < LL) lab = labels[b * LL + lane];
    const int labprev = __shfl_up(lab, 1);
    const bool cs = (lane > 0) && (lane < LL) && (lab != labprev);
    const bool is16 = (lane == 16), is32 = (lane == 32), is48 = (lane == 48);

    const float* p = y + (size_t)b * TT * CC + lab;    // per-lane column

    float A[BS], B[BS], C[BS];
    float a0 = (lane == 0) ? 1.0f : 0.0f;              // uniform t=0 update -> alpha0
    float a1 = 0.0f;
    int lg = 0;

#define ISSUE(buf, bi_) do {                                              \
    const int _t0 = (bi_) * BS;                                           \
    _Pragma("unroll")                                                     \
    for (int _j = 0; _j < BS; ++_j) {                                     \
        int _t = _t0 + _j; _t = (_t < TT) ? _t : (TT - 1); /* clamp */    \
        (buf)[_j] = p[(size_t)_t * CC];                                   \
    } } while (0)

#define PIN(buf) do {                                                     \
    _Pragma("unroll")                                                     \
    for (int _j = 0; _j < BS; ++_j)                                       \
        asm volatile("" : "+v"((buf)[_j]));  /* value pin, no mem clobber */ \
    } while (0)

#define STEP(pv) do {                                                     \
    const float _pl = (pv) + EPS;                                         \
    const float _pb = rdlane((pv), 63) + EPS;   /* blank (lane63) */      \
    float _pp = dpp_mv<0x111>(a1);              /* a1[l-1], row_shr:1 */  \
    const float _s15 = rdlane(a1, 15);                                    \
    const float _s31 = rdlane(a1, 31);                                    \
    const float _s47 = rdlane(a1, 47);                                    \
    if (is16) _pp = _s15;                                                 \
    if (is32) _pp = _s31;                                                 \
    if (is48) _pp = _s47;                       /* lane0 keeps 0 */       \
    const float _a0o = a0;                                                \
    a0 = (_a0o + _pp) * _pb;                                              \
    a1 = (a1 + _a0o + (cs ? _pp : 0.0f)) * _pl;                           \
    } while (0)

#define RESCALE do {                                                      \
    float _m = fmaxf(a0, a1);                                             \
    _m = fmaxf(_m, dpp_mv<0x111>(_m));                                    \
    _m = fmaxf(_m, dpp_mv<0x112>(_m));                                    \
    _m = fmaxf(_m, dpp_mv<0x114>(_m));                                    \
    _m = fmaxf(_m, dpp_mv<0x118>(_m));                                    \
    _m = fmaxf(_m, dpp_mv<0x142>(_m));                                    \
    _m = fmaxf(_m, dpp_mv<0x143>(_m));                                    \
    const float _mm = rdlane(_m, 63);                                     \
    int _e; (void)frexpf(_mm, &_e);                                       \
    a0 = ldexpf(a0, -_e);                                                 \
    a1 = ldexpf(a1, -_e);                                                 \
    lg += _e;                                                             \
    } while (0)

#define BODY(cons, dst, bi_) do {                                         \
    ISSUE(dst, (bi_) + 2);            /* loads 2 bodies ahead */          \
    PIN(cons);                        /* batch bi_ must be materialized */ \
    _Pragma("unroll")                                                     \
    for (int _k = 0; _k < BS; ++_k) {                                     \
        STEP((cons)[_k]);                                                 \
        if ((_k & 7) == 7) RESCALE;                                       \
    } } while (0)

    ISSUE(A, 0);
    ISSUE(B, 1);
    for (int i = 0; i < NB - 1; i += 3) {   // bodies 0..14 (batch i lives in {A,B,C}[i%3])
        BODY(A, C, i);
        BODY(B, A, i + 1);
        BODY(C, B, i + 2);
    }
    BODY(A, C, NB - 1);                     // body 15 (15%3==0 -> in A)

    // loss = -( log(alpha[95] + alpha[96]) + lg*ln2 )
    const float v95 = rdlane(a1, 47);
    const float v96 = rdlane(a0, 48);
    if (lane == 0) {
        const float s = fmaxf(v95 + v96, 1e-37f);
        out[b] = -(__logf(s) + (float)lg * 0.69314718056f);
    }

#undef ISSUE
#undef PIN
#undef STEP
#undef RESCALE
#undef BODY
}

extern "C" void kernel_launch(void* const* d_in, const int* in_sizes, int n_in,
                              void* d_out, int out_size, void* d_ws, size_t ws_size,
                              hipStream_t stream) {
    const float* y = (const float*)d_in[0];
    const int* labels = (const int*)d_in[1];
    float* out = (float*)d_out;
    const int B = in_sizes[0] / (TT * CC);   // 1024
    ctc_fwd_v6<<<B / 4, 256, 0, stream>>>(y, labels, out);
}